// Round 5
// baseline (608.591 us; speedup 1.0000x reference)
//
#include <hip/hip_runtime.h>
#include <stdint.h>

#define NN 8192
#define CC 128
#define BN_EPS 1e-5f

__device__ inline unsigned short f2bf(float f) {
    unsigned int u = __float_as_uint(f);
    unsigned int r = (u + 0x7fffu + ((u >> 16) & 1u)) >> 16;   // RNE
    return (unsigned short)r;
}

// ---------------------------------------------------------------------------
// Kernel 1a: compress binary A into a bit-transposed mask + degrees.
//   Mt[band * 8192 + i] : u64 word, bit b set iff A[band*64 + b][i] != 0
//   deg[j]              : rowsum of A[j,:] (float)
// One wave per 64x128 tile (128 bands x 64 col-tiles = 8192 waves -> 8/SIMD).
// (byte-identical to the round-3 version — R4 showed orientation is neutral)
// ---------------------------------------------------------------------------
__global__ __launch_bounds__(256, 8) void k1a_mask(
        const float* __restrict__ A, unsigned long long* __restrict__ Mt,
        float* __restrict__ deg) {
    __shared__ float dred[4][64];
    const int lane = threadIdx.x & 63;
    const int wave = threadIdx.x >> 6;
    const int task = blockIdx.x * 4 + wave;     // 0..8191
    const int band = task >> 6;                 // 0..127
    const int i0   = (task & 63) << 7;          // col tile * 128
    const int j0   = band << 6;                 // row band * 64

    const uint2* Ap = reinterpret_cast<const uint2*>(A + (size_t)j0 * NN + i0) + lane;
    unsigned long long m0 = 0, m1 = 0;
    float degc = 0.0f;

    #pragma unroll 8
    for (int j = 0; j < 64; ++j) {
        uint2 v = Ap[(size_t)j * (NN / 2)];     // 0.0f or 1.0f -> bit test
        bool n0 = v.x != 0u, n1 = v.y != 0u;
        unsigned long long b0 = __ballot(n0), b1 = __ballot(n1);
        const unsigned long long bit = 1ull << j;
        if (n0) m0 |= bit;
        if (n1) m1 |= bit;
        if (lane == j) degc = (float)(__popcll(b0) + __popcll(b1));
    }

    unsigned long long* p = Mt + (size_t)band * NN + i0 + 2 * lane;
    *reinterpret_cast<ulonglong2*>(p) = make_ulonglong2(m0, m1);

    dred[wave][lane] = degc;
    __syncthreads();
    if (wave == 0) {
        float s = dred[0][lane] + dred[1][lane] + dred[2][lane] + dred[3][lane];
        atomicAdd(&deg[j0 + lane], s);
    }
}

// ---------------------------------------------------------------------------
// Kernel 1c v3: aggN[i,:] = (1/deg[i]) * sum_{j : A[j,i]!=0} X[j,:]
// One BLOCK per FOUR rows i0..i0+3 (consecutive i share Mt cache lines ->
// line-amplified Mt traffic /4). Two phases:
//  decode: 512 words scanned with r as the fast index (4 consecutive i per
//          32B chunk, coalesced); set bits appended to a flat LDS list.
//  gather: list sliced evenly across 4 waves (kills binomial imbalance);
//          4 entries / 8 loads in flight per iteration; LDS float atomics
//          (c = lane -> 2 lanes/bank, conflict-free).
// ---------------------------------------------------------------------------
__global__ __launch_bounds__(256, 8) void k1c_gather(
        const unsigned long long* __restrict__ Mt, const float* __restrict__ X,
        const float* __restrict__ deg, float* __restrict__ aggN) {
    __shared__ float acc[4][128];
    __shared__ int   idx[2048];                 // (r<<13)|j ; way past any max
    __shared__ int   cnt;
    const int tid  = threadIdx.x;
    const int lane = tid & 63;
    const int wave = tid >> 6;
    const int i0   = blockIdx.x * 4;

    if (tid == 0) cnt = 0;
    {
        float* a = &acc[0][0];
        a[tid] = 0.0f; a[256 + tid] = 0.0f;
    }
    __syncthreads();

    // ---- decode: thread t scans words s = t, t+256 (s = w*4 + r) ----
    #pragma unroll
    for (int s = tid; s < 512; s += 256) {
        int r = s & 3;
        int w = s >> 2;
        unsigned long long m = Mt[(size_t)w * NN + i0 + r];
        while (m) {
            int b = __builtin_ctzll(m); m &= m - 1;
            int e = atomicAdd(&cnt, 1);
            idx[e] = (r << 13) | (w * 64 + b);
        }
    }
    __syncthreads();
    const int n  = cnt;
    const int t0 = (n * wave) >> 2;
    const int t1 = (n * (wave + 1)) >> 2;

    // ---- gather: 4-deep pipeline, 8 loads in flight ----
    int t = t0;
    for (; t + 4 <= t1; t += 4) {
        int e0 = idx[t], e1 = idx[t + 1], e2 = idx[t + 2], e3 = idx[t + 3];
        const float* p0 = X + (size_t)(e0 & 8191) * CC;
        const float* p1 = X + (size_t)(e1 & 8191) * CC;
        const float* p2 = X + (size_t)(e2 & 8191) * CC;
        const float* p3 = X + (size_t)(e3 & 8191) * CC;
        float v00 = p0[lane], v01 = p0[64 + lane];
        float v10 = p1[lane], v11 = p1[64 + lane];
        float v20 = p2[lane], v21 = p2[64 + lane];
        float v30 = p3[lane], v31 = p3[64 + lane];
        atomicAdd(&acc[e0 >> 13][lane], v00); atomicAdd(&acc[e0 >> 13][64 + lane], v01);
        atomicAdd(&acc[e1 >> 13][lane], v10); atomicAdd(&acc[e1 >> 13][64 + lane], v11);
        atomicAdd(&acc[e2 >> 13][lane], v20); atomicAdd(&acc[e2 >> 13][64 + lane], v21);
        atomicAdd(&acc[e3 >> 13][lane], v30); atomicAdd(&acc[e3 >> 13][64 + lane], v31);
    }
    for (; t < t1; ++t) {
        int e0 = idx[t];
        const float* p0 = X + (size_t)(e0 & 8191) * CC;
        float v00 = p0[lane], v01 = p0[64 + lane];
        atomicAdd(&acc[e0 >> 13][lane], v00); atomicAdd(&acc[e0 >> 13][64 + lane], v01);
    }
    __syncthreads();

    // ---- finalize: 512 outputs, coalesced (threads 0..127 = row i0) ----
    #pragma unroll
    for (int s = tid; s < 512; s += 256) {
        int r = s >> 7, c = s & 127;
        float d  = deg[i0 + r];
        float rd = (d == 0.0f) ? 1.0f : (1.0f / d);
        aggN[(size_t)(i0 + r) * CC + c] = acc[r][c] * rd;
    }
}

// ---------------------------------------------------------------------------
// Kernel 2: h = aggN @ Wn^T + X @ Wc^T + bn + bc, fused BN partial sums.
// Fused LDS array Wp[swz(k*128+c)] = bf16(Wn)|bf16(Wc)<<16, XOR swizzle
// ^(k&31): conflict-free reads, one ds_read_b32 per (k, both weights).
// (unchanged — verified -13.7 us in R3)
// ---------------------------------------------------------------------------
__global__ __launch_bounds__(256, 2) void k2_gemm(
        const float* __restrict__ aggN, const float* __restrict__ X,
        const float* __restrict__ Wn, const float* __restrict__ bn,
        const float* __restrict__ Wc, const float* __restrict__ bc,
        float* __restrict__ h, float* __restrict__ bsum, float* __restrict__ bsq) {
    __shared__ unsigned int Wp[128 * 128];      // 64 KB -> 2 blocks/CU
    const int tid = threadIdx.x;
    for (int idx = tid * 4; idx < 128 * 128; idx += 1024) {
        float4 wn4 = *reinterpret_cast<const float4*>(Wn + idx);
        float4 wc4 = *reinterpret_cast<const float4*>(Wc + idx);
        int c = idx >> 7, k0 = idx & 127;       // 4 consecutive k, same c
        #pragma unroll
        for (int q = 0; q < 4; ++q) {
            unsigned int pk = (unsigned int)f2bf((&wn4.x)[q])
                            | ((unsigned int)f2bf((&wc4.x)[q]) << 16);
            int k = k0 + q;
            Wp[(k * 128 + c) ^ (k & 31)] = pk;
        }
    }
    __syncthreads();
    const int c  = tid & 127;
    const int rg = tid >> 7;
    const int i0 = blockIdx.x * 16 + rg * 8;

    float accN[8], accC[8];
    #pragma unroll
    for (int r = 0; r < 8; ++r) { accN[r] = 0.0f; accC[r] = 0.0f; }

    float4 ar[8], xr[8], an[8], xn[8];

#define LOADK(ab_, xb_, k_) do {                                               \
    _Pragma("unroll")                                                          \
    for (int r = 0; r < 8; ++r) {                                              \
        ab_[r] = *reinterpret_cast<const float4*>(&aggN[(size_t)(i0 + r) * CC + (k_)]); \
        xb_[r] = *reinterpret_cast<const float4*>(&X[(size_t)(i0 + r) * CC + (k_)]);    \
    }                                                                          \
} while (0)

#define COMPK(ab_, xb_, k_) do {                                               \
    _Pragma("unroll")                                                          \
    for (int kk = 0; kk < 4; ++kk) {                                           \
        int kq_ = (k_) + kk;                                                   \
        unsigned int pk_ = Wp[(kq_ * 128 + c) ^ (kq_ & 31)];                   \
        float wn_ = __uint_as_float(pk_ << 16);                                \
        float wc_ = __uint_as_float(pk_ & 0xffff0000u);                        \
        _Pragma("unroll")                                                      \
        for (int r = 0; r < 8; ++r) {                                          \
            accN[r] = fmaf((&ab_[r].x)[kk], wn_, accN[r]);                     \
            accC[r] = fmaf((&xb_[r].x)[kk], wc_, accC[r]);                     \
        }                                                                      \
    }                                                                          \
} while (0)

    LOADK(ar, xr, 0);
    for (int k = 0; k < 128; k += 8) {
        LOADK(an, xn, k + 4);
        COMPK(ar, xr, k);
        if (k + 8 < 128) LOADK(ar, xr, k + 8);
        COMPK(an, xn, k + 4);
    }

    const float bnc = bn[c], bcc = bc[c];
    float sp = 0.0f, sq = 0.0f;
    #pragma unroll
    for (int r = 0; r < 8; ++r) {
        float hv = accN[r] + accC[r] + bnc + bcc;
        h[(size_t)(i0 + r) * CC + c] = hv;
        sp += hv; sq += hv * hv;
    }
    __syncthreads();                              // Wp reads done; reuse as fp32 scratch
    float* red = reinterpret_cast<float*>(Wp);
    red[rg * 128 + c]       = sp;
    red[256 + rg * 128 + c] = sq;
    __syncthreads();
    if (rg == 0) {
        atomicAdd(&bsum[c], red[c] + red[128 + c]);
        atomicAdd(&bsq[c],  red[256 + c] + red[384 + c]);
    }
}

// ---------------------------------------------------------------------------
// Kernel 3: out = relu(gamma * (h - mu) * rsqrt(var + eps) + beta), float4.
// ---------------------------------------------------------------------------
__global__ __launch_bounds__(256) void k4_bn(
        const float* __restrict__ h, const float* __restrict__ bsum,
        const float* __restrict__ bsq, const float* __restrict__ gamma,
        const float* __restrict__ beta, float* __restrict__ out) {
    const int idx = (blockIdx.x * 256 + threadIdx.x) * 4;
    const int c0  = idx & 127;
    float4 hv = *reinterpret_cast<const float4*>(h + idx);
    float4 s4 = *reinterpret_cast<const float4*>(bsum + c0);
    float4 q4 = *reinterpret_cast<const float4*>(bsq + c0);
    float4 g4 = *reinterpret_cast<const float4*>(gamma + c0);
    float4 b4 = *reinterpret_cast<const float4*>(beta + c0);
    const float invN = 1.0f / 8192.0f;
    float4 o;
    const float* hp = &hv.x; const float* sp = &s4.x; const float* qp = &q4.x;
    const float* gp = &g4.x; const float* bp = &b4.x; float* op = &o.x;
    #pragma unroll
    for (int jj = 0; jj < 4; ++jj) {
        float mu  = sp[jj] * invN;
        float var = qp[jj] * invN - mu * mu;
        float sc  = gp[jj] * rsqrtf(var + BN_EPS);
        float v   = (hp[jj] - mu) * sc + bp[jj];
        op[jj] = v > 0.0f ? v : 0.0f;
    }
    *reinterpret_cast<float4*>(out + idx) = o;
}

extern "C" void kernel_launch(void* const* d_in, const int* in_sizes, int n_in,
                              void* d_out, int out_size, void* d_ws, size_t ws_size,
                              hipStream_t stream) {
    const float* X     = (const float*)d_in[0];   // [8192,128]
    const float* A     = (const float*)d_in[1];   // [8192,8192]
    const float* Wn    = (const float*)d_in[2];   // [128,128]
    const float* bn    = (const float*)d_in[3];
    const float* Wc    = (const float*)d_in[4];
    const float* bc    = (const float*)d_in[5];
    const float* gamma = (const float*)d_in[6];
    const float* beta  = (const float*)d_in[7];
    float* out = (float*)d_out;

    // Workspace layout (12.65 MB) — identical to round 3:
    //   deg   @ 0        (32 KB, zeroed)
    //   bsum  @ 32768    (512 B, zeroed)
    //   bsq   @ 33280    (512 B, zeroed)
    //   aggN  @ 65536    (4 MB, fully written by k1c)
    //   Mt    @ 4259840  (8 MB, fully written by k1a)
    //   h     aliases Mt (Mt dead after k1c; k2 writes h before k4 reads)
    char* ws = (char*)d_ws;
    float* deg  = (float*)(ws);
    float* bsum = (float*)(ws + 32768);
    float* bsq  = (float*)(ws + 33280);
    float* aggN = (float*)(ws + 65536);
    unsigned long long* Mt = (unsigned long long*)(ws + 4259840);
    float* h    = (float*)(ws + 4259840);

    hipMemsetAsync(d_ws, 0, 33792, stream);

    k1a_mask  <<<2048, 256, 0, stream>>>(A, Mt, deg);
    k1c_gather<<<2048, 256, 0, stream>>>(Mt, X, deg, aggN);
    k2_gemm   <<<512,  256, 0, stream>>>(aggN, X, Wn, bn, Wc, bc, h, bsum, bsq);
    k4_bn     <<<1024, 256, 0, stream>>>(h, bsum, bsq, gamma, beta, out);
}

// Round 6
// 459.298 us; speedup vs baseline: 1.3250x; 1.3250x over previous
//
#include <hip/hip_runtime.h>
#include <stdint.h>

#define NN 8192
#define CC 128
#define BN_EPS 1e-5f

__device__ inline unsigned short f2bf(float f) {
    unsigned int u = __float_as_uint(f);
    unsigned int r = (u + 0x7fffu + ((u >> 16) & 1u)) >> 16;   // RNE
    return (unsigned short)r;
}

// ---------------------------------------------------------------------------
// Kernel 1a v3: compress binary A into bit-transposed mask + degrees.
//   Mt[band * 8192 + i] : u64 word, bit b set iff A[band*64 + b][i] != 0
//   deg[j]              : rowsum of A[j,:] (float)
// MLP restructure (R5 analysis: old version kept ~2 loads in flight ->
// 2.9 TB/s latency-bound): tile 64 rows x 256 cols, uint4/lane, explicit
// load-8-rows-to-regs THEN process-8 split => 8 KB in flight per wave.
// Lane l owns cols i0+4l..+3 (m0..m3), stores 32 B dense -> same Mt layout
// as before (word index == column index); k1c unchanged.
// 128 bands x 32 tiles = 4096 waves; 1024 blocks = 4/CU = 16 waves/CU.
// ---------------------------------------------------------------------------
__global__ __launch_bounds__(256, 4) void k1a_mask(
        const float* __restrict__ A, unsigned long long* __restrict__ Mt,
        float* __restrict__ deg) {
    __shared__ float dred[4][64];
    const int lane = threadIdx.x & 63;
    const int wave = threadIdx.x >> 6;
    const int task = blockIdx.x * 4 + wave;     // 0..4095
    const int band = task >> 5;                 // 0..127  (32%4==0: block-uniform)
    const int i0   = (task & 31) << 8;          // col tile * 256
    const int j0   = band << 6;                 // row band * 64

    const uint4* Ap = reinterpret_cast<const uint4*>(A + (size_t)j0 * NN + i0) + lane;
    unsigned long long m0 = 0, m1 = 0, m2 = 0, m3 = 0;
    int degc = 0;

    #pragma unroll
    for (int t = 0; t < 8; ++t) {
        uint4 v[8];
        #pragma unroll
        for (int u = 0; u < 8; ++u)             // 8 independent 1 KB loads
            v[u] = Ap[(size_t)(t * 8 + u) * (NN / 4)];
        #pragma unroll
        for (int u = 0; u < 8; ++u) {
            const int j = t * 8 + u;
            bool n0 = v[u].x != 0u, n1 = v[u].y != 0u;
            bool n2 = v[u].z != 0u, n3 = v[u].w != 0u;
            unsigned long long b0 = __ballot(n0), b1 = __ballot(n1);
            unsigned long long b2 = __ballot(n2), b3 = __ballot(n3);
            const unsigned long long bit = 1ull << j;
            if (n0) m0 |= bit;
            if (n1) m1 |= bit;
            if (n2) m2 |= bit;
            if (n3) m3 |= bit;
            int cnt = __popcll(b0) + __popcll(b1) + __popcll(b2) + __popcll(b3);
            if (lane == j) degc = cnt;          // lane j owns row j0+j's count
        }
    }

    unsigned long long* p = Mt + (size_t)band * NN + i0 + 4 * lane;
    reinterpret_cast<ulonglong2*>(p)[0] = make_ulonglong2(m0, m1);
    reinterpret_cast<ulonglong2*>(p)[1] = make_ulonglong2(m2, m3);

    dred[wave][lane] = (float)degc;
    __syncthreads();
    if (wave == 0) {
        float s = dred[0][lane] + dred[1][lane] + dred[2][lane] + dred[3][lane];
        atomicAdd(&deg[j0 + lane], s);
    }
}

// ---------------------------------------------------------------------------
// Kernel 1c: aggN[i,:] = (1/deg[i]) * sum_{j : A[j,i]!=0} X[j,:]
// One BLOCK per output row i; 4 waves split the 128 mask words, LDS reduce.
// (byte-identical to the round-3 version — proven ~33 us; R5 variant reverted)
// ---------------------------------------------------------------------------
__global__ __launch_bounds__(256, 8) void k1c_gather(
        const unsigned long long* __restrict__ Mt, const float* __restrict__ X,
        const float* __restrict__ deg, float* __restrict__ aggN) {
    __shared__ float red[4][128];
    const int lane = threadIdx.x & 63;
    const int wave = threadIdx.x >> 6;
    const int i = blockIdx.x;

    unsigned long long w = 0;
    if (lane < 32)
        w = Mt[(size_t)(wave * 32 + lane) * NN + i];
    float acc0 = 0.0f, acc1 = 0.0f;

    unsigned long long any = __ballot(w != 0ull);   // bits only in lanes 0..31
    while (any) {
        int q = __builtin_ctzll(any); any &= any - 1;
        unsigned long long u = __shfl(w, q);
        const float* Xq = X + (size_t)((wave * 32 + q) * 64) * CC;
        while (u) {
            int b = __builtin_ctzll(u); u &= u - 1;
            const float* xr = Xq + b * CC;
            acc0 += xr[lane];
            acc1 += xr[64 + lane];
        }
    }

    red[wave][lane]      = acc0;
    red[wave][64 + lane] = acc1;
    __syncthreads();
    if (wave == 0) {
        float s0 = red[0][lane]      + red[1][lane]      + red[2][lane]      + red[3][lane];
        float s1 = red[0][64 + lane] + red[1][64 + lane] + red[2][64 + lane] + red[3][64 + lane];
        float d  = deg[i];
        float rd = (d == 0.0f) ? 1.0f : (1.0f / d);
        aggN[(size_t)i * CC + lane]      = s0 * rd;
        aggN[(size_t)i * CC + 64 + lane] = s1 * rd;
    }
}

// ---------------------------------------------------------------------------
// Kernel 2: h = aggN @ Wn^T + X @ Wc^T + bn + bc, fused BN partial sums.
// Fused LDS array Wp[swz(k*128+c)] = bf16(Wn)|bf16(Wc)<<16, XOR swizzle
// ^(k&31): conflict-free reads, one ds_read_b32 per (k, both weights).
// (unchanged — verified -13.7 us in R3)
// ---------------------------------------------------------------------------
__global__ __launch_bounds__(256, 2) void k2_gemm(
        const float* __restrict__ aggN, const float* __restrict__ X,
        const float* __restrict__ Wn, const float* __restrict__ bn,
        const float* __restrict__ Wc, const float* __restrict__ bc,
        float* __restrict__ h, float* __restrict__ bsum, float* __restrict__ bsq) {
    __shared__ unsigned int Wp[128 * 128];      // 64 KB -> 2 blocks/CU
    const int tid = threadIdx.x;
    for (int idx = tid * 4; idx < 128 * 128; idx += 1024) {
        float4 wn4 = *reinterpret_cast<const float4*>(Wn + idx);
        float4 wc4 = *reinterpret_cast<const float4*>(Wc + idx);
        int c = idx >> 7, k0 = idx & 127;       // 4 consecutive k, same c
        #pragma unroll
        for (int q = 0; q < 4; ++q) {
            unsigned int pk = (unsigned int)f2bf((&wn4.x)[q])
                            | ((unsigned int)f2bf((&wc4.x)[q]) << 16);
            int k = k0 + q;
            Wp[(k * 128 + c) ^ (k & 31)] = pk;
        }
    }
    __syncthreads();
    const int c  = tid & 127;
    const int rg = tid >> 7;
    const int i0 = blockIdx.x * 16 + rg * 8;

    float accN[8], accC[8];
    #pragma unroll
    for (int r = 0; r < 8; ++r) { accN[r] = 0.0f; accC[r] = 0.0f; }

    float4 ar[8], xr[8], an[8], xn[8];

#define LOADK(ab_, xb_, k_) do {                                               \
    _Pragma("unroll")                                                          \
    for (int r = 0; r < 8; ++r) {                                              \
        ab_[r] = *reinterpret_cast<const float4*>(&aggN[(size_t)(i0 + r) * CC + (k_)]); \
        xb_[r] = *reinterpret_cast<const float4*>(&X[(size_t)(i0 + r) * CC + (k_)]);    \
    }                                                                          \
} while (0)

#define COMPK(ab_, xb_, k_) do {                                               \
    _Pragma("unroll")                                                          \
    for (int kk = 0; kk < 4; ++kk) {                                           \
        int kq_ = (k_) + kk;                                                   \
        unsigned int pk_ = Wp[(kq_ * 128 + c) ^ (kq_ & 31)];                   \
        float wn_ = __uint_as_float(pk_ << 16);                                \
        float wc_ = __uint_as_float(pk_ & 0xffff0000u);                        \
        _Pragma("unroll")                                                      \
        for (int r = 0; r < 8; ++r) {                                          \
            accN[r] = fmaf((&ab_[r].x)[kk], wn_, accN[r]);                     \
            accC[r] = fmaf((&xb_[r].x)[kk], wc_, accC[r]);                     \
        }                                                                      \
    }                                                                          \
} while (0)

    LOADK(ar, xr, 0);
    for (int k = 0; k < 128; k += 8) {
        LOADK(an, xn, k + 4);
        COMPK(ar, xr, k);
        if (k + 8 < 128) LOADK(ar, xr, k + 8);
        COMPK(an, xn, k + 4);
    }

    const float bnc = bn[c], bcc = bc[c];
    float sp = 0.0f, sq = 0.0f;
    #pragma unroll
    for (int r = 0; r < 8; ++r) {
        float hv = accN[r] + accC[r] + bnc + bcc;
        h[(size_t)(i0 + r) * CC + c] = hv;
        sp += hv; sq += hv * hv;
    }
    __syncthreads();                              // Wp reads done; reuse as fp32 scratch
    float* red = reinterpret_cast<float*>(Wp);
    red[rg * 128 + c]       = sp;
    red[256 + rg * 128 + c] = sq;
    __syncthreads();
    if (rg == 0) {
        atomicAdd(&bsum[c], red[c] + red[128 + c]);
        atomicAdd(&bsq[c],  red[256 + c] + red[384 + c]);
    }
}

// ---------------------------------------------------------------------------
// Kernel 3: out = relu(gamma * (h - mu) * rsqrt(var + eps) + beta), float4.
// ---------------------------------------------------------------------------
__global__ __launch_bounds__(256) void k4_bn(
        const float* __restrict__ h, const float* __restrict__ bsum,
        const float* __restrict__ bsq, const float* __restrict__ gamma,
        const float* __restrict__ beta, float* __restrict__ out) {
    const int idx = (blockIdx.x * 256 + threadIdx.x) * 4;
    const int c0  = idx & 127;
    float4 hv = *reinterpret_cast<const float4*>(h + idx);
    float4 s4 = *reinterpret_cast<const float4*>(bsum + c0);
    float4 q4 = *reinterpret_cast<const float4*>(bsq + c0);
    float4 g4 = *reinterpret_cast<const float4*>(gamma + c0);
    float4 b4 = *reinterpret_cast<const float4*>(beta + c0);
    const float invN = 1.0f / 8192.0f;
    float4 o;
    const float* hp = &hv.x; const float* sp = &s4.x; const float* qp = &q4.x;
    const float* gp = &g4.x; const float* bp = &b4.x; float* op = &o.x;
    #pragma unroll
    for (int jj = 0; jj < 4; ++jj) {
        float mu  = sp[jj] * invN;
        float var = qp[jj] * invN - mu * mu;
        float sc  = gp[jj] * rsqrtf(var + BN_EPS);
        float v   = (hp[jj] - mu) * sc + bp[jj];
        op[jj] = v > 0.0f ? v : 0.0f;
    }
    *reinterpret_cast<float4*>(out + idx) = o;
}

extern "C" void kernel_launch(void* const* d_in, const int* in_sizes, int n_in,
                              void* d_out, int out_size, void* d_ws, size_t ws_size,
                              hipStream_t stream) {
    const float* X     = (const float*)d_in[0];   // [8192,128]
    const float* A     = (const float*)d_in[1];   // [8192,8192]
    const float* Wn    = (const float*)d_in[2];   // [128,128]
    const float* bn    = (const float*)d_in[3];
    const float* Wc    = (const float*)d_in[4];
    const float* bc    = (const float*)d_in[5];
    const float* gamma = (const float*)d_in[6];
    const float* beta  = (const float*)d_in[7];
    float* out = (float*)d_out;

    // Workspace layout (12.65 MB) — identical to round 3:
    //   deg   @ 0        (32 KB, zeroed)
    //   bsum  @ 32768    (512 B, zeroed)
    //   bsq   @ 33280    (512 B, zeroed)
    //   aggN  @ 65536    (4 MB, fully written by k1c)
    //   Mt    @ 4259840  (8 MB, fully written by k1a)
    //   h     aliases Mt (Mt dead after k1c; k2 writes h before k4 reads)
    char* ws = (char*)d_ws;
    float* deg  = (float*)(ws);
    float* bsum = (float*)(ws + 32768);
    float* bsq  = (float*)(ws + 33280);
    float* aggN = (float*)(ws + 65536);
    unsigned long long* Mt = (unsigned long long*)(ws + 4259840);
    float* h    = (float*)(ws + 4259840);

    hipMemsetAsync(d_ws, 0, 33792, stream);

    k1a_mask  <<<1024, 256, 0, stream>>>(A, Mt, deg);
    k1c_gather<<<8192, 256, 0, stream>>>(Mt, X, deg, aggN);
    k2_gemm   <<<512,  256, 0, stream>>>(aggN, X, Wn, bn, Wc, bc, h, bsum, bsq);
    k4_bn     <<<1024, 256, 0, stream>>>(h, bsum, bsq, gamma, beta, out);
}

// Round 7
// 457.849 us; speedup vs baseline: 1.3292x; 1.0032x over previous
//
#include <hip/hip_runtime.h>
#include <stdint.h>

#define NN 8192
#define CC 128
#define BN_EPS 1e-5f

__device__ inline unsigned short f2bf(float f) {
    unsigned int u = __float_as_uint(f);
    unsigned int r = (u + 0x7fffu + ((u >> 16) & 1u)) >> 16;   // RNE
    return (unsigned short)r;
}

// ---------------------------------------------------------------------------
// Kernel 1a v4: memcpy-pattern stream of A -> row-major bitmask + degrees.
//   chunk g = (row j = g>>5, col-chunk t = g&31) covers cols [256t, 256t+256)
//   M[j*128 + 4t + q] : u64, bit l = (A[j][256t + 4l + q] != 0)
//   deg[j]            : rowsum of A[j,:] (atomic, 32 partials/row)
// Grid-stride over chunks: at iter k the 8192 waves cover chunks
// [k*8192,(k+1)*8192) = a CONTIGUOUS 8 MB window — aggregate access pattern
// identical to the 6.7 TB/s fill (R4/R6 falsified per-wave-shape theories;
// remaining model is HBM row-buffer locality of the AGGREGATE stream).
// ---------------------------------------------------------------------------
__global__ __launch_bounds__(256, 8) void k1a_stream(
        const float* __restrict__ A, unsigned long long* __restrict__ M,
        float* __restrict__ deg) {
    const int lane = threadIdx.x & 63;
    const int wid  = (blockIdx.x << 2) + (threadIdx.x >> 6);   // 0..8191
    for (int it = 0; it < 32; ++it) {
        const int g = wid + (it << 13);         // chunk index
        const int j = g >> 5;                   // row
        const int t = g & 31;                   // 256-col chunk
        const uint4 v = *(reinterpret_cast<const uint4*>(A + ((size_t)j << 13))
                          + (t << 6) + lane);   // 1 KB contiguous per wave
        unsigned long long b0 = __ballot(v.x != 0u);
        unsigned long long b1 = __ballot(v.y != 0u);
        unsigned long long b2 = __ballot(v.z != 0u);
        unsigned long long b3 = __ballot(v.w != 0u);
        int cnt = __popcll(b0) + __popcll(b1) + __popcll(b2) + __popcll(b3);
        unsigned long long w = (lane == 0) ? b0 : (lane == 1) ? b1
                             : (lane == 2) ? b2 : b3;
        if (lane < 4)
            M[(size_t)j * 128 + (t << 2) + lane] = w;    // 32 B, lanes 0..3
        if (lane == 0 && cnt)
            atomicAdd(&deg[j], (float)cnt);
    }
}

// ---------------------------------------------------------------------------
// Kernel 1b: 64x64 bit-block transpose M -> Mt (bit dim: i -> j).
//   Mt[band*8192 + v] (v = W*64 + l) : u64, bit b = A[band*64 + b][col(W,l)]
//   col(W,l) = 256*(W>>2) + 4*l + (W&3)   (k1a ballot order; absorbed by k1c)
// Block = (band, 32-word-col tile): stage 64x32 u64 to LDS (pad 33 -> b64
// column reads at the 4-way floor), per word-col a 6-step __shfl_xor bit
// butterfly (element (r,c) swaps r<->c bit by bit-level), contiguous 512-B
// stores. 16 MB L3-resident traffic + ~0.7M VALU-instr total => ~6 us.
// ---------------------------------------------------------------------------
__global__ __launch_bounds__(256, 8) void k1b_bitT(
        const unsigned long long* __restrict__ M,
        unsigned long long* __restrict__ Mt) {
    __shared__ unsigned long long lds[64 * 33];
    const int tid  = threadIdx.x;
    const int lane = tid & 63;
    const int wave = tid >> 6;
    const int band = blockIdx.x >> 2;           // 0..127
    const int W0   = (blockIdx.x & 3) << 5;     // word-col tile * 32
    const int j0   = band << 6;

    #pragma unroll
    for (int e = tid; e < 2048; e += 256) {
        int jj = e >> 5, ww = e & 31;
        lds[jj * 33 + ww] = M[(size_t)(j0 + jj) * 128 + W0 + ww];
    }
    __syncthreads();

    #pragma unroll
    for (int s = 0; s < 8; ++s) {
        const int ww = (wave << 3) + s;
        unsigned long long x = lds[lane * 33 + ww];   // row = lane
        #pragma unroll
        for (int st = 0; st < 6; ++st) {
            const int jd = 1 << st;
            const unsigned long long m =
                (st == 0) ? 0x5555555555555555ull :
                (st == 1) ? 0x3333333333333333ull :
                (st == 2) ? 0x0F0F0F0F0F0F0F0Full :
                (st == 3) ? 0x00FF00FF00FF00FFull :
                (st == 4) ? 0x0000FFFF0000FFFFull :
                            0x00000000FFFFFFFFull;    // bits with (c & jd)==0
            unsigned long long p = __shfl_xor(x, jd);
            if ((lane & jd) == 0) {                   // low row of the pair
                unsigned long long tt = ((x >> jd) ^ p) & m;
                x ^= (tt << jd);
            } else {                                  // high row
                unsigned long long tt = ((p >> jd) ^ x) & m;
                x ^= tt;
            }
        }
        // lane l now holds: bit b = original row (j0+b), col(W0+ww, l)
        Mt[(size_t)band * NN + ((W0 + ww) << 6) + lane] = x;
    }
}

// ---------------------------------------------------------------------------
// Kernel 1c: aggN[i,:] = (1/deg[i]) * sum_{j : A[j,i]!=0} X[j,:]
// One BLOCK per Mt column v; 4 waves split the 128 bands, LDS reduce.
// Memory pattern byte-identical to the proven R3 version (~33 us); the only
// change is the block->output-row map i = sigma(v) undoing k1a's ballot
// order (verified: A[5][1000] -> M[5][12].b58 -> Mt[826].b5 -> i=1000).
// ---------------------------------------------------------------------------
__global__ __launch_bounds__(256, 8) void k1c_gather(
        const unsigned long long* __restrict__ Mt, const float* __restrict__ X,
        const float* __restrict__ deg, float* __restrict__ aggN) {
    __shared__ float red[4][128];
    const int lane = threadIdx.x & 63;
    const int wave = threadIdx.x >> 6;
    const int v = blockIdx.x;
    const int W = v >> 6;
    const int i = ((W >> 2) << 8) + ((v & 63) << 2) + (W & 3);

    unsigned long long w = 0;
    if (lane < 32)
        w = Mt[(size_t)(wave * 32 + lane) * NN + v];
    float acc0 = 0.0f, acc1 = 0.0f;

    unsigned long long any = __ballot(w != 0ull);   // bits only in lanes 0..31
    while (any) {
        int q = __builtin_ctzll(any); any &= any - 1;
        unsigned long long u = __shfl(w, q);
        const float* Xq = X + (size_t)((wave * 32 + q) * 64) * CC;
        while (u) {
            int b = __builtin_ctzll(u); u &= u - 1;
            const float* xr = Xq + b * CC;
            acc0 += xr[lane];
            acc1 += xr[64 + lane];
        }
    }

    red[wave][lane]      = acc0;
    red[wave][64 + lane] = acc1;
    __syncthreads();
    if (wave == 0) {
        float s0 = red[0][lane]      + red[1][lane]      + red[2][lane]      + red[3][lane];
        float s1 = red[0][64 + lane] + red[1][64 + lane] + red[2][64 + lane] + red[3][64 + lane];
        float d  = deg[i];
        float rd = (d == 0.0f) ? 1.0f : (1.0f / d);
        aggN[(size_t)i * CC + lane]      = s0 * rd;
        aggN[(size_t)i * CC + 64 + lane] = s1 * rd;
    }
}

// ---------------------------------------------------------------------------
// Kernel 2: h = aggN @ Wn^T + X @ Wc^T + bn + bc, fused BN partial sums.
// Fused LDS array Wp[swz(k*128+c)] = bf16(Wn)|bf16(Wc)<<16, XOR swizzle
// ^(k&31): conflict-free reads, one ds_read_b32 per (k, both weights).
// (unchanged — verified -13.7 us in R3)
// ---------------------------------------------------------------------------
__global__ __launch_bounds__(256, 2) void k2_gemm(
        const float* __restrict__ aggN, const float* __restrict__ X,
        const float* __restrict__ Wn, const float* __restrict__ bn,
        const float* __restrict__ Wc, const float* __restrict__ bc,
        float* __restrict__ h, float* __restrict__ bsum, float* __restrict__ bsq) {
    __shared__ unsigned int Wp[128 * 128];      // 64 KB -> 2 blocks/CU
    const int tid = threadIdx.x;
    for (int idx = tid * 4; idx < 128 * 128; idx += 1024) {
        float4 wn4 = *reinterpret_cast<const float4*>(Wn + idx);
        float4 wc4 = *reinterpret_cast<const float4*>(Wc + idx);
        int c = idx >> 7, k0 = idx & 127;       // 4 consecutive k, same c
        #pragma unroll
        for (int q = 0; q < 4; ++q) {
            unsigned int pk = (unsigned int)f2bf((&wn4.x)[q])
                            | ((unsigned int)f2bf((&wc4.x)[q]) << 16);
            int k = k0 + q;
            Wp[(k * 128 + c) ^ (k & 31)] = pk;
        }
    }
    __syncthreads();
    const int c  = tid & 127;
    const int rg = tid >> 7;
    const int i0 = blockIdx.x * 16 + rg * 8;

    float accN[8], accC[8];
    #pragma unroll
    for (int r = 0; r < 8; ++r) { accN[r] = 0.0f; accC[r] = 0.0f; }

    float4 ar[8], xr[8], an[8], xn[8];

#define LOADK(ab_, xb_, k_) do {                                               \
    _Pragma("unroll")                                                          \
    for (int r = 0; r < 8; ++r) {                                              \
        ab_[r] = *reinterpret_cast<const float4*>(&aggN[(size_t)(i0 + r) * CC + (k_)]); \
        xb_[r] = *reinterpret_cast<const float4*>(&X[(size_t)(i0 + r) * CC + (k_)]);    \
    }                                                                          \
} while (0)

#define COMPK(ab_, xb_, k_) do {                                               \
    _Pragma("unroll")                                                          \
    for (int kk = 0; kk < 4; ++kk) {                                           \
        int kq_ = (k_) + kk;                                                   \
        unsigned int pk_ = Wp[(kq_ * 128 + c) ^ (kq_ & 31)];                   \
        float wn_ = __uint_as_float(pk_ << 16);                                \
        float wc_ = __uint_as_float(pk_ & 0xffff0000u);                        \
        _Pragma("unroll")                                                      \
        for (int r = 0; r < 8; ++r) {                                          \
            accN[r] = fmaf((&ab_[r].x)[kk], wn_, accN[r]);                     \
            accC[r] = fmaf((&xb_[r].x)[kk], wc_, accC[r]);                     \
        }                                                                      \
    }                                                                          \
} while (0)

    LOADK(ar, xr, 0);
    for (int k = 0; k < 128; k += 8) {
        LOADK(an, xn, k + 4);
        COMPK(ar, xr, k);
        if (k + 8 < 128) LOADK(ar, xr, k + 8);
        COMPK(an, xn, k + 4);
    }

    const float bnc = bn[c], bcc = bc[c];
    float sp = 0.0f, sq = 0.0f;
    #pragma unroll
    for (int r = 0; r < 8; ++r) {
        float hv = accN[r] + accC[r] + bnc + bcc;
        h[(size_t)(i0 + r) * CC + c] = hv;
        sp += hv; sq += hv * hv;
    }
    __syncthreads();                              // Wp reads done; reuse as fp32 scratch
    float* red = reinterpret_cast<float*>(Wp);
    red[rg * 128 + c]       = sp;
    red[256 + rg * 128 + c] = sq;
    __syncthreads();
    if (rg == 0) {
        atomicAdd(&bsum[c], red[c] + red[128 + c]);
        atomicAdd(&bsq[c],  red[256 + c] + red[384 + c]);
    }
}

// ---------------------------------------------------------------------------
// Kernel 3: out = relu(gamma * (h - mu) * rsqrt(var + eps) + beta), float4.
// ---------------------------------------------------------------------------
__global__ __launch_bounds__(256) void k4_bn(
        const float* __restrict__ h, const float* __restrict__ bsum,
        const float* __restrict__ bsq, const float* __restrict__ gamma,
        const float* __restrict__ beta, float* __restrict__ out) {
    const int idx = (blockIdx.x * 256 + threadIdx.x) * 4;
    const int c0  = idx & 127;
    float4 hv = *reinterpret_cast<const float4*>(h + idx);
    float4 s4 = *reinterpret_cast<const float4*>(bsum + c0);
    float4 q4 = *reinterpret_cast<const float4*>(bsq + c0);
    float4 g4 = *reinterpret_cast<const float4*>(gamma + c0);
    float4 b4 = *reinterpret_cast<const float4*>(beta + c0);
    const float invN = 1.0f / 8192.0f;
    float4 o;
    const float* hp = &hv.x; const float* sp = &s4.x; const float* qp = &q4.x;
    const float* gp = &g4.x; const float* bp = &b4.x; float* op = &o.x;
    #pragma unroll
    for (int jj = 0; jj < 4; ++jj) {
        float mu  = sp[jj] * invN;
        float var = qp[jj] * invN - mu * mu;
        float sc  = gp[jj] * rsqrtf(var + BN_EPS);
        float v   = (hp[jj] - mu) * sc + bp[jj];
        op[jj] = v > 0.0f ? v : 0.0f;
    }
    *reinterpret_cast<float4*>(out + idx) = o;
}

extern "C" void kernel_launch(void* const* d_in, const int* in_sizes, int n_in,
                              void* d_out, int out_size, void* d_ws, size_t ws_size,
                              hipStream_t stream) {
    const float* X     = (const float*)d_in[0];   // [8192,128]
    const float* A     = (const float*)d_in[1];   // [8192,8192]
    const float* Wn    = (const float*)d_in[2];   // [128,128]
    const float* bn    = (const float*)d_in[3];
    const float* Wc    = (const float*)d_in[4];
    const float* bc    = (const float*)d_in[5];
    const float* gamma = (const float*)d_in[6];
    const float* beta  = (const float*)d_in[7];
    float* out = (float*)d_out;

    // Workspace layout (20.1 MB):
    //   deg   @ 0        (32 KB, zeroed — atomic partials)
    //   bsum  @ 32768    (512 B, zeroed)
    //   bsq   @ 33280    (512 B, zeroed)
    //   aggN  @ 65536    (4 MB, fully written by k1c)
    //   M     @ 4259840  (8 MB, row-major mask; dead after k1b)
    //   Mt    @ 12648448 (8 MB, bit-transposed mask)
    //   h     aliases M  (k2 writes h after k1b's last M read)
    char* ws = (char*)d_ws;
    float* deg  = (float*)(ws);
    float* bsum = (float*)(ws + 32768);
    float* bsq  = (float*)(ws + 33280);
    float* aggN = (float*)(ws + 65536);
    unsigned long long* M  = (unsigned long long*)(ws + 4259840);
    unsigned long long* Mt = (unsigned long long*)(ws + 12648448);
    float* h    = (float*)(ws + 4259840);

    hipMemsetAsync(d_ws, 0, 33792, stream);

    k1a_stream<<<2048, 256, 0, stream>>>(A, M, deg);
    k1b_bitT  <<<512,  256, 0, stream>>>(M, Mt);
    k1c_gather<<<8192, 256, 0, stream>>>(Mt, X, deg, aggN);
    k2_gemm   <<<512,  256, 0, stream>>>(aggN, X, Wn, bn, Wc, bc, h, bsum, bsq);
    k4_bn     <<<1024, 256, 0, stream>>>(h, bsum, bsq, gamma, beta, out);
}